// Round 1
// 474.041 us; speedup vs baseline: 1.0852x; 1.0852x over previous
//
#include <hip/hip_runtime.h>

// Problem constants (fixed by setup_inputs: B=16, Cin=Cout=64, H=W=224,
// K=3, pad=1, stride=1, PH=PW=32, version=3).
constexpr int B_ = 16, C_ = 64, H_ = 224, W_ = 224;
constexpr int PH_ = 32, PW_ = 32;
constexpr int PLANE  = H_ * W_;          // 50176
constexpr int GROW   = W_ / 16;          // 14 groups of 16 floats per row
constexpr int GPLANE = PLANE / 16;       // 3136 groups per plane
constexpr unsigned TOTAL16 = (unsigned)B_ * C_ * GPLANE;   // 3,211,264

constexpr int CONV_BLOCKS = 256;         // 16 batches x 16 cout-groups (4 couts)
constexpr int COPY_BLOCKS = 1792;
constexpr int THREADS = 256;
constexpr unsigned COPY_STRIDE = (unsigned)COPY_BLOCKS * THREADS;  // 458,752
constexpr int COPY_ITERS = (int)(TOTAL16 / COPY_STRIDE);           // exactly 7

// Conv over one batch's 32x32 patch for 4 consecutive couts.
// Thread tile: 1 output row x 4 cols x 4 couts. 256 threads = 32 rows x 8 colgrps.
// Per cin: 18 shared input loads (3 rows x 6 cols) feed 144 FMAs.
// EDGE=true adds lower-bound zero-pad guards (only needed when y==0 or x==0;
// upper bounds can never be exceeded since y,x <= 191).
template <bool EDGE>
__device__ __forceinline__ void conv_patch(
    int b, int co0, int tid, int y, int x,
    const float* __restrict__ in, const float* __restrict__ bias,
    float* __restrict__ out, const float4* wlds)
{
    const int colg = tid & 7;        // 0..7  -> output cols ox0..ox0+3
    const int oy   = tid >> 3;       // 0..31 -> output row
    const int ox0  = colg * 4;
    const float* inb = in + (size_t)b * C_ * PLANE;

    float acc[4][4];                 // [col k][cout j]
#pragma unroll
    for (int k = 0; k < 4; ++k)
#pragma unroll
        for (int j = 0; j < 4; ++j) acc[k][j] = 0.f;

    const int cbase = x + ox0 - 1;   // leftmost input col this thread touches
    const int rbase = y + oy - 1;    // topmost input row

#pragma unroll 1
    for (int cin = 0; cin < C_; ++cin) {
        const float* ip = inb + cin * PLANE;

        float4 w[9];
#pragma unroll
        for (int t = 0; t < 9; ++t) w[t] = wlds[cin * 9 + t];  // LDS broadcast

        // Load the full 3x6 input window first (one big load cluster).
        float v[3][6];
#pragma unroll
        for (int dy = 0; dy < 3; ++dy) {
            const int ri = rbase + dy;
            const float* rowp = ip + ri * W_;
#pragma unroll
            for (int dx = 0; dx < 6; ++dx) {
                const int ci = cbase + dx;
                if (EDGE) {
                    float t = 0.f;
                    if (ri >= 0 && ci >= 0) t = rowp[ci];
                    v[dy][dx] = t;
                } else {
                    v[dy][dx] = rowp[ci];
                }
            }
        }

#pragma unroll
        for (int k = 0; k < 4; ++k)
#pragma unroll
            for (int dy = 0; dy < 3; ++dy)
#pragma unroll
                for (int d = 0; d < 3; ++d) {
                    const float4 wv = w[dy * 3 + d];
                    const float vv = v[dy][k + d];
                    acc[k][0] += vv * wv.x;
                    acc[k][1] += vv * wv.y;
                    acc[k][2] += vv * wv.z;
                    acc[k][3] += vv * wv.w;
                }
    }

    float bs[4];
#pragma unroll
    for (int j = 0; j < 4; ++j) bs[j] = bias[co0 + j];

    const int orow = y + oy;
#pragma unroll
    for (int j = 0; j < 4; ++j) {
        float* op = out + (size_t)(b * C_ + co0 + j) * PLANE + orow * W_ + (x + ox0);
#pragma unroll
        for (int k = 0; k < 4; ++k) op[k] = acc[k][j] + bs[j];
    }
}

__global__ __launch_bounds__(THREADS) void inc_conv_fused(
    const float* __restrict__ in, const float* __restrict__ wt,
    const float* __restrict__ bias, const float* __restrict__ stale,
    const int* __restrict__ loc, float* __restrict__ out)
{
    __shared__ float4 wlds[C_ * 9];   // [cin*9 + tap] -> weights for 4 couts
    __shared__ int    locs[2 * B_];

    const int tid = threadIdx.x;
    const int bid = blockIdx.x;

    if (bid < CONV_BLOCKS) {
        // ---------------- conv blocks: write exactly the patch region -------
        const int b   = bid >> 4;
        const int co0 = (bid & 15) * 4;

        // Stage weights: wt[co][cin*9+tap] -> wlds[cin*9+tap] = {co0..co0+3}
        for (int idx = tid; idx < C_ * 9; idx += THREADS) {
            float4 wv;
            wv.x = wt[(co0 + 0) * C_ * 9 + idx];
            wv.y = wt[(co0 + 1) * C_ * 9 + idx];
            wv.z = wt[(co0 + 2) * C_ * 9 + idx];
            wv.w = wt[(co0 + 3) * C_ * 9 + idx];
            wlds[idx] = wv;
        }
        __syncthreads();

        const int y = loc[2 * b], x = loc[2 * b + 1];
        if (y > 0 && x > 0)
            conv_patch<false>(b, co0, tid, y, x, in, bias, out, wlds);
        else
            conv_patch<true>(b, co0, tid, y, x, in, bias, out, wlds);
    } else {
        // ---------------- copy blocks: everything EXCEPT the patch region ---
        if (tid < 2 * B_) locs[tid] = loc[tid];
        __syncthreads();

        const float4* __restrict__ src4 = (const float4*)stale;
        float4* __restrict__ dst4 = (float4*)out;

        // Each iteration handles one row-aligned group of 16 floats (64 B).
        unsigned i = (unsigned)(bid - CONV_BLOCKS) * THREADS + tid;

        float4 v0, v1, v2, v3;
        {
            const size_t q = (size_t)i * 4;
            v0 = src4[q]; v1 = src4[q + 1]; v2 = src4[q + 2]; v3 = src4[q + 3];
        }

#pragma unroll
        for (int it = 0; it < COPY_ITERS; ++it) {
            const unsigned ni = i + COPY_STRIDE;
            float4 n0, n1, n2, n3;
            if (it < COPY_ITERS - 1) {
                const size_t q = (size_t)ni * 4;   // issue next loads early
                n0 = src4[q]; n1 = src4[q + 1]; n2 = src4[q + 2]; n3 = src4[q + 3];
            } else {
                n0 = v0; n1 = v1; n2 = v2; n3 = v3;
            }

            // Map group index -> (b, h, c0). 16-float groups never cross rows.
            const unsigned plane = i / GPLANE;          // magic-mul
            const unsigned rem   = i - plane * GPLANE;
            const unsigned h     = rem / GROW;          // magic-mul
            const unsigned c0    = (rem - h * GROW) * 16;
            const unsigned b     = plane >> 6;          // 64 planes per batch
            const unsigned yy = (unsigned)locs[2 * b];
            const unsigned xx = (unsigned)locs[2 * b + 1];

            const bool inrow = (h - yy) < (unsigned)PH_;
            const bool ovl = inrow & (c0 + 15 >= xx) & (c0 <= xx + (PW_ - 1));

            const size_t q = (size_t)i * 4;
            if (!ovl) {
                dst4[q] = v0; dst4[q + 1] = v1; dst4[q + 2] = v2; dst4[q + 3] = v3;
            } else {
                // partial/full overlap with patch cols: store only outside cols
                const float vf[16] = {v0.x, v0.y, v0.z, v0.w,
                                      v1.x, v1.y, v1.z, v1.w,
                                      v2.x, v2.y, v2.z, v2.w,
                                      v3.x, v3.y, v3.z, v3.w};
                float* dstf = out + q * 4;
#pragma unroll
                for (int k = 0; k < 16; ++k) {
                    if ((c0 + k - xx) >= (unsigned)PW_) dstf[k] = vf[k];
                }
            }

            v0 = n0; v1 = n1; v2 = n2; v3 = n3;
            i = ni;
        }
    }
}

extern "C" void kernel_launch(void* const* d_in, const int* in_sizes, int n_in,
                              void* d_out, int out_size, void* d_ws, size_t ws_size,
                              hipStream_t stream) {
    const float* in   = (const float*)d_in[0];  // (16,64,224,224) fp32
    const float* wt   = (const float*)d_in[1];  // (64,64,3,3) fp32
    const float* bias = (const float*)d_in[2];  // (64,) fp32
    const float* st   = (const float*)d_in[3];  // (16,64,224,224) fp32 stale out
    const int*   loc  = (const int*)d_in[4];    // (16,2) int32 (y,x)
    float* out = (float*)d_out;

    inc_conv_fused<<<dim3(CONV_BLOCKS + COPY_BLOCKS), dim3(THREADS), 0, stream>>>(
        in, wt, bias, st, loc, out);
}

// Round 2
// 454.509 us; speedup vs baseline: 1.1318x; 1.0430x over previous
//
#include <hip/hip_runtime.h>

// Problem constants (fixed by setup_inputs: B=16, Cin=Cout=64, H=W=224,
// K=3, pad=1, stride=1, PH=PW=32, version=3).
constexpr int B_ = 16, C_ = 64, H_ = 224, W_ = 224;
constexpr int PH_ = 32, PW_ = 32;
constexpr int PLANE  = H_ * W_;          // 50176
constexpr int PLANE4 = PLANE / 4;        // 12544 float4 per (b,c) plane
constexpr int ROW4   = W_ / 4;           // 56 float4 per row
constexpr unsigned TOTAL4 = (unsigned)B_ * C_ * PLANE4;   // 12,845,056

constexpr int CONV_BLOCKS = 256;         // 16 batches x 16 cout-groups (4 couts)
constexpr int COPY_BLOCKS = 1792;
constexpr int THREADS = 256;
constexpr unsigned G_LANES = (unsigned)COPY_BLOCKS * THREADS;   // 458,752
constexpr int ELEMS_PER_LANE = (int)(TOTAL4 / G_LANES);         // exactly 28
constexpr int BATCH  = 4;
constexpr int NBATCH = ELEMS_PER_LANE / BATCH;                  // exactly 7

using f32x4 = __attribute__((ext_vector_type(4))) float;

// Conv over one batch's 32x32 patch for 4 consecutive couts.
// Thread tile: 1 output row x 4 cols x 4 couts. 256 threads = 32 rows x 8 colgrps.
// Per cin: 18 shared input loads (3 rows x 6 cols) feed 144 FMAs.
// EDGE=true adds lower-bound zero-pad guards (only needed when y==0 or x==0;
// upper bounds can never be exceeded since y,x <= 191).
template <bool EDGE>
__device__ __forceinline__ void conv_patch(
    int b, int co0, int tid, int y, int x,
    const float* __restrict__ in, const float* __restrict__ bias,
    float* __restrict__ out, const float4* wlds)
{
    const int colg = tid & 7;        // 0..7  -> output cols ox0..ox0+3
    const int oy   = tid >> 3;       // 0..31 -> output row
    const int ox0  = colg * 4;
    const float* inb = in + (size_t)b * C_ * PLANE;

    float acc[4][4];                 // [col k][cout j]
#pragma unroll
    for (int k = 0; k < 4; ++k)
#pragma unroll
        for (int j = 0; j < 4; ++j) acc[k][j] = 0.f;

    const int cbase = x + ox0 - 1;   // leftmost input col this thread touches
    const int rbase = y + oy - 1;    // topmost input row

#pragma unroll 1
    for (int cin = 0; cin < C_; ++cin) {
        const float* ip = inb + cin * PLANE;

        float4 w[9];
#pragma unroll
        for (int t = 0; t < 9; ++t) w[t] = wlds[cin * 9 + t];  // LDS broadcast

        // Load the full 3x6 input window first (one big load cluster).
        float v[3][6];
#pragma unroll
        for (int dy = 0; dy < 3; ++dy) {
            const int ri = rbase + dy;
            const float* rowp = ip + ri * W_;
#pragma unroll
            for (int dx = 0; dx < 6; ++dx) {
                const int ci = cbase + dx;
                if (EDGE) {
                    float t = 0.f;
                    if (ri >= 0 && ci >= 0) t = rowp[ci];
                    v[dy][dx] = t;
                } else {
                    v[dy][dx] = rowp[ci];
                }
            }
        }

#pragma unroll
        for (int k = 0; k < 4; ++k)
#pragma unroll
            for (int dy = 0; dy < 3; ++dy)
#pragma unroll
                for (int d = 0; d < 3; ++d) {
                    const float4 wv = w[dy * 3 + d];
                    const float vv = v[dy][k + d];
                    acc[k][0] += vv * wv.x;
                    acc[k][1] += vv * wv.y;
                    acc[k][2] += vv * wv.z;
                    acc[k][3] += vv * wv.w;
                }
    }

    float bs[4];
#pragma unroll
    for (int j = 0; j < 4; ++j) bs[j] = bias[co0 + j];

    const int orow = y + oy;
#pragma unroll
    for (int j = 0; j < 4; ++j) {
        float* op = out + (size_t)(b * C_ + co0 + j) * PLANE + orow * W_ + (x + ox0);
#pragma unroll
        for (int k = 0; k < 4; ++k) op[k] = acc[k][j] + bs[j];
    }
}

__global__ __launch_bounds__(THREADS) void inc_conv_fused(
    const float* __restrict__ in, const float* __restrict__ wt,
    const float* __restrict__ bias, const float* __restrict__ stale,
    const int* __restrict__ loc, float* __restrict__ out)
{
    __shared__ float4 wlds[C_ * 9];   // [cin*9 + tap] -> weights for 4 couts
    __shared__ int    locs[2 * B_];

    const int tid = threadIdx.x;
    const int bid = blockIdx.x;

    if (bid < CONV_BLOCKS) {
        // ---------------- conv blocks: write exactly the patch region -------
        const int b   = bid >> 4;
        const int co0 = (bid & 15) * 4;

        // Stage weights: wt[co][cin*9+tap] -> wlds[cin*9+tap] = {co0..co0+3}
        for (int idx = tid; idx < C_ * 9; idx += THREADS) {
            float4 wv;
            wv.x = wt[(co0 + 0) * C_ * 9 + idx];
            wv.y = wt[(co0 + 1) * C_ * 9 + idx];
            wv.z = wt[(co0 + 2) * C_ * 9 + idx];
            wv.w = wt[(co0 + 3) * C_ * 9 + idx];
            wlds[idx] = wv;
        }
        __syncthreads();

        const int y = loc[2 * b], x = loc[2 * b + 1];
        if (y > 0 && x > 0)
            conv_patch<false>(b, co0, tid, y, x, in, bias, out, wlds);
        else
            conv_patch<true>(b, co0, tid, y, x, in, bias, out, wlds);
    } else {
        // ---------------- copy blocks: everything EXCEPT the patch region ---
        if (tid < 2 * B_) locs[tid] = loc[tid];
        __syncthreads();

        const f32x4* __restrict__ src4 = (const f32x4*)stale;
        f32x4* __restrict__ dst4 = (f32x4*)out;

        // Lane handles 28 float4s at grid-lane stride G_LANES: every load and
        // store instruction is unit-stride across lanes (fully coalesced),
        // grouped into 7 batches of 4 with a 2-stage pipeline (8 loads in
        // flight per lane).
        const unsigned base = (unsigned)(bid - CONV_BLOCKS) * THREADS + tid;

        f32x4 cur[BATCH];
#pragma unroll
        for (int j = 0; j < BATCH; ++j)
            cur[j] = __builtin_nontemporal_load(
                src4 + base + (unsigned)j * G_LANES);

#pragma unroll
        for (int it = 0; it < NBATCH; ++it) {
            f32x4 nxt[BATCH];
            if (it + 1 < NBATCH) {
#pragma unroll
                for (int j = 0; j < BATCH; ++j)
                    nxt[j] = __builtin_nontemporal_load(
                        src4 + base + (unsigned)((it + 1) * BATCH + j) * G_LANES);
            }

#pragma unroll
            for (int j = 0; j < BATCH; ++j) {
                const unsigned e = base + (unsigned)(it * BATCH + j) * G_LANES;
                // Map float4 index -> (b, h, c0).
                const unsigned plane = e / PLANE4;          // magic-mul
                const unsigned p     = e - plane * PLANE4;
                const unsigned h     = p / ROW4;            // magic-mul
                const unsigned c0    = (p - h * ROW4) * 4;
                const unsigned b     = plane >> 6;          // 64 planes/batch
                const int yy = locs[2 * b];
                const int xx = locs[2 * b + 1];

                const bool inrow = (h - (unsigned)yy) < (unsigned)PH_;
                const bool ovl = inrow & ((int)c0 + 3 >= xx) &
                                 ((int)c0 <= xx + (PW_ - 1));
                if (!ovl) {
                    __builtin_nontemporal_store(cur[j], dst4 + e);   // fast path
                } else {
                    // partial/full overlap with patch cols: store only outside
                    float* dstf = out + (size_t)e * 4;
#pragma unroll
                    for (int k = 0; k < 4; ++k) {
                        const unsigned c = c0 + k;
                        if ((c - (unsigned)xx) >= (unsigned)PW_)
                            dstf[k] = cur[j][k];
                    }
                }
            }

            if (it + 1 < NBATCH) {
#pragma unroll
                for (int j = 0; j < BATCH; ++j) cur[j] = nxt[j];
            }
        }
    }
}

extern "C" void kernel_launch(void* const* d_in, const int* in_sizes, int n_in,
                              void* d_out, int out_size, void* d_ws, size_t ws_size,
                              hipStream_t stream) {
    const float* in   = (const float*)d_in[0];  // (16,64,224,224) fp32
    const float* wt   = (const float*)d_in[1];  // (64,64,3,3) fp32
    const float* bias = (const float*)d_in[2];  // (64,) fp32
    const float* st   = (const float*)d_in[3];  // (16,64,224,224) fp32 stale out
    const int*   loc  = (const int*)d_in[4];    // (16,2) int32 (y,x)
    float* out = (float*)d_out;

    inc_conv_fused<<<dim3(CONV_BLOCKS + COPY_BLOCKS), dim3(THREADS), 0, stream>>>(
        in, wt, bias, st, loc, out);
}